// Round 3
// baseline (1104.116 us; speedup 1.0000x reference)
//
#include <hip/hip_runtime.h>

#define LEN 4096
#define FRAME 1024
#define DCH 128
#define NFR 4

// top-4 insert: val desc, idx asc tiebreak (matches jax.lax.top_k stability)
#define TOPK_INSERT(vv, bb)                                                     \
    {                                                                           \
        float v_ = (vv); int b_ = (bb);                                         \
        bool c0 = (v_ > tv0) || (v_ == tv0 && b_ < ti0);                        \
        bool c1 = (v_ > tv1) || (v_ == tv1 && b_ < ti1);                        \
        bool c2 = (v_ > tv2) || (v_ == tv2 && b_ < ti2);                        \
        bool c3 = (v_ > tv3) || (v_ == tv3 && b_ < ti3);                        \
        tv3 = c3 ? (c2 ? tv2 : v_) : tv3; ti3 = c3 ? (c2 ? ti2 : b_) : ti3;     \
        tv2 = c2 ? (c1 ? tv1 : v_) : tv2; ti2 = c2 ? (c1 ? ti1 : b_) : ti2;     \
        tv1 = c1 ? (c0 ? tv0 : v_) : tv1; ti1 = c1 ? (c0 ? ti0 : b_) : ti1;     \
        tv0 = c0 ? v_ : tv0;              ti0 = c0 ? b_ : ti0;                  \
    }

// ---------------------------------------------------------------------------
// Kernel 1: fused S-GEMM (S = Q_tq * V_tk^T) + 9-point band-sum + running
// top-4, written directly.
// grid 512 = n(2)*tq(4)*tk(4)*ab(16), IDENTITY block order (consecutive
// blocks share (n,tq,tk) -> same V slab stream; round-1-proven L2 behavior).
// Each WG: 64 a-rows (S rows A0-32..A0+95, 128 rows) x all 1024 b, as 16
// slabs of 2 b-image-rows. corr window in registers (4 slots x 4 wb).
// LDS 46KB -> 2 blocks/CU at grid 512. Reg-staged global prefetch per chunk.
// ---------------------------------------------------------------------------
__global__ __launch_bounds__(512, 4) void corr_topk_kernel(
    const float* __restrict__ query,
    const float* __restrict__ value,
    int* __restrict__ idx_out)
{
    __shared__ __align__(16) float Ssl[128 * 65];   // 33,280 B
    __shared__ __align__(16) float Qc[16 * 132];    //  8,448 B (k-major)
    __shared__ __align__(16) float Vc[16 * 66];     //  4,224 B (k-major)

    const int wg = blockIdx.x;
    const int ab = wg & 15;
    const int tk = (wg >> 4) & 3;
    const int tq = (wg >> 6) & 3;
    const int n  = wg >> 8;
    const int A0 = ab * 64;

    const float* __restrict__ Qf = query + (size_t)((n * NFR + tq) * FRAME) * DCH;
    const float* __restrict__ Vf = value + (size_t)((n * NFR + tk) * FRAME) * DCH;

    const int tid = threadIdx.x;
    const int rg  = tid & 15;     // GEMM rows rg*8 .. rg*8+7
    const int cg  = tid >> 4;     // GEMM cols cg*2, cg*2+1
    const int a_loc = tid >> 3;   // 0..63 : topk row a = A0 + a_loc
    const int wq    = tid & 7;    // wb quad: wb = wq*4 + u
    const int wa = a_loc & 31;    // (A0 multiple of 64 -> (A0+a_loc)&31 == a_loc&31)
    const int ha = (A0 + a_loc) >> 5;

    // staging roles: every thread 1 Q float4; tid<256 also 1 V float4
    const int k4 = (tid & 3) * 4;
    const int r0 = tid >> 2;                       // Q row 0..127
    const int agl0 = A0 - 32 + r0;
    const bool ok0 = (unsigned)agl0 < (unsigned)FRAME;
    const float* gq = Qf + (size_t)(ok0 ? agl0 : 0) * DCH + k4;
    const bool hasV = tid < 256;
    const int rv = tid >> 2;                       // V row 0..63 (when hasV)

    float cr[16];
    #pragma unroll
    for (int i = 0; i < 16; ++i) cr[i] = 0.0f;

    float tv0 = -3.402823466e38f, tv1 = tv0, tv2 = tv0, tv3 = tv0;
    int   ti0 = 0x7fffffff, ti1 = ti0, ti2 = ti0, ti3 = ti0;

#define ACC_TERM(SLOT, HP, DI) do {                                             \
    if ((unsigned)(ha + (DI)) < 32u) {                                          \
        const float* Sr = &Ssl[(a_loc + 32 + (DI) * 32) * 65 + (HP) * 32 + wq * 4]; \
        _Pragma("unroll")                                                       \
        for (int u = 0; u < 4; ++u) {                                           \
            float s = Sr[u];                                                    \
            if ((wa > 0)  && ((u > 0) || (wq > 0))) s += Sr[u - 66];            \
            if ((wa < 31) && ((u < 3) || (wq < 7))) s += Sr[u + 66];            \
            cr[(SLOT) * 4 + u] += s;                                            \
        }                                                                       \
    }                                                                           \
} while (0)

#define FINALIZE_ROW(HB, SLOT) do {                                             \
    const int hbg_ = (HB);                                                      \
    _Pragma("unroll")                                                           \
    for (int u = 0; u < 4; ++u) {                                               \
        TOPK_INSERT(cr[(SLOT) * 4 + u], hbg_ * 32 + wq * 4 + u);                \
        cr[(SLOT) * 4 + u] = 0.0f;                                              \
    }                                                                           \
} while (0)

    for (int p = 0; p < 16; ++p) {
        float acc[16];
        #pragma unroll
        for (int i = 0; i < 16; ++i) acc[i] = 0.0f;

        const float* gv = Vf + (size_t)(p * 64 + rv) * DCH + k4;

        // preload chunk 0
        float4 g0 = make_float4(0.f, 0.f, 0.f, 0.f);
        if (ok0) g0 = *reinterpret_cast<const float4*>(gq);
        float4 g1 = make_float4(0.f, 0.f, 0.f, 0.f);
        if (hasV) g1 = *reinterpret_cast<const float4*>(gv);

        for (int kc = 0; kc < 8; ++kc) {
            __syncthreads();        // previous chunk's compute done
            Qc[(k4 + 0) * 132 + r0] = g0.x;
            Qc[(k4 + 1) * 132 + r0] = g0.y;
            Qc[(k4 + 2) * 132 + r0] = g0.z;
            Qc[(k4 + 3) * 132 + r0] = g0.w;
            if (hasV) {
                Vc[(k4 + 0) * 66 + rv] = g1.x;
                Vc[(k4 + 1) * 66 + rv] = g1.y;
                Vc[(k4 + 2) * 66 + rv] = g1.z;
                Vc[(k4 + 3) * 66 + rv] = g1.w;
            }
            __syncthreads();        // writes visible
            if (kc < 7) {           // prefetch next chunk (hides under compute)
                const int off = (kc + 1) * 16;
                if (ok0) g0 = *reinterpret_cast<const float4*>(gq + off);
                if (hasV) g1 = *reinterpret_cast<const float4*>(gv + off);
            }
            #pragma unroll
            for (int k = 0; k < 16; ++k) {
                const float* qr = &Qc[k * 132 + rg * 8];
                float4 q0 = *reinterpret_cast<const float4*>(qr);
                float4 q1 = *reinterpret_cast<const float4*>(qr + 4);
                float2 vv = *reinterpret_cast<const float2*>(&Vc[k * 66 + cg * 2]);
                float qv[8];
                qv[0] = q0.x; qv[1] = q0.y; qv[2] = q0.z; qv[3] = q0.w;
                qv[4] = q1.x; qv[5] = q1.y; qv[6] = q1.z; qv[7] = q1.w;
                #pragma unroll
                for (int i = 0; i < 8; ++i) {
                    acc[2 * i + 0] = fmaf(qv[i], vv.x, acc[2 * i + 0]);
                    acc[2 * i + 1] = fmaf(qv[i], vv.y, acc[2 * i + 1]);
                }
            }
        }
        __syncthreads();
        #pragma unroll
        for (int i = 0; i < 8; ++i) {
            Ssl[(rg * 8 + i) * 65 + cg * 2 + 0] = acc[2 * i + 0];
            Ssl[(rg * 8 + i) * 65 + cg * 2 + 1] = acc[2 * i + 1];
        }
        __syncthreads();

        // band-sum accumulate (output rows 2p-1..2p+2) + finalize rows 2p-1,2p
        if (p & 1) {
            ACC_TERM(1, 0, +1);
            ACC_TERM(2, 0,  0); ACC_TERM(2, 1, +1);
            ACC_TERM(3, 0, -1); ACC_TERM(3, 1,  0);
            if (p < 15) ACC_TERM(0, 1, -1);
            FINALIZE_ROW(2 * p - 1, 1);
            FINALIZE_ROW(2 * p,     2);
        } else {
            if (p > 0) ACC_TERM(3, 0, +1);
            ACC_TERM(0, 0,  0); ACC_TERM(0, 1, +1);
            ACC_TERM(1, 0, -1); ACC_TERM(1, 1,  0);
            ACC_TERM(2, 1, -1);
            if (p > 0) FINALIZE_ROW(2 * p - 1, 3);
            FINALIZE_ROW(2 * p, 0);
        }
    }
    FINALIZE_ROW(31, 3);   // last output row (p=15 leaves row 31 in slot 3)

    // merge top-4 across the 8 wq lanes (adjacent lanes, same wave)
    #pragma unroll
    for (int m = 1; m <= 4; m <<= 1) {
        float ov0 = __shfl_xor(tv0, m); int oi0 = __shfl_xor(ti0, m);
        float ov1 = __shfl_xor(tv1, m); int oi1 = __shfl_xor(ti1, m);
        float ov2 = __shfl_xor(tv2, m); int oi2 = __shfl_xor(ti2, m);
        float ov3 = __shfl_xor(tv3, m); int oi3 = __shfl_xor(ti3, m);
        TOPK_INSERT(ov0, oi0);
        TOPK_INSERT(ov1, oi1);
        TOPK_INSERT(ov2, oi2);
        TOPK_INSERT(ov3, oi3);
    }

    if (wq == 0) {
        const int q = tq * FRAME + A0 + a_loc;
        int4 st; st.x = ti0; st.y = ti1; st.z = ti2; st.w = ti3;
        *reinterpret_cast<int4*>(idx_out + (size_t)((n * LEN + q) * NFR + tk) * 4) = st;
    }
#undef ACC_TERM
#undef FINALIZE_ROW
}

// ---------------------------------------------------------------------------
// Kernel 2: W_out transpose.
// ---------------------------------------------------------------------------
__global__ void wt_kernel(const float* __restrict__ W, float* __restrict__ WT)
{
    int i = blockIdx.x * 256 + threadIdx.x;   // 16384
    int c = i >> 7, dd = i & 127;
    WT[c * 128 + dd] = W[dd * 128 + c];
}

// ---------------------------------------------------------------------------
// Kernel 3: sampling_locations.
// ---------------------------------------------------------------------------
__global__ void sloc_kernel(const int* __restrict__ idxb, float* __restrict__ slout)
{
    int gid = blockIdx.x * 256 + threadIdx.x;     // < 1179648
    int pp = gid & 3;
    int t1 = gid >> 2;
    int j  = t1 % 9;
    int t2 = t1 / 9;
    int t  = t2 & 3;
    int q  = (t2 >> 2) & 4095;
    int n  = t2 >> 14;
    int sel = idxb[((n * LEN + q) * NFR + t) * 4 + pp];
    int shift = (j / 3 - 1) * 32 + (j % 3 - 1);
    int r = sel + shift;
    r = r < 0 ? 0 : (r > 961 ? 961 : r);
    float2 loc = make_float2((float)(r >> 5) * (1.0f / 32.0f),
                             (float)(r & 31) * (1.0f / 32.0f));
    *reinterpret_cast<float2*>(slout + (size_t)gid * 2) = loc;
}

// ---------------------------------------------------------------------------
// Kernel 4: gather + bilinear (weights exactly 0.25) + fused projection.
// Interior fast path: 3x3 shifts x 2x2 taps collapse to a 4x4 stencil with
// [1,2,2,1] (x) [1,2,2,1] counts. Branch is block-uniform (sel shared).
// Identity block order (round-2 swizzle reverted).
// ---------------------------------------------------------------------------
__global__ __launch_bounds__(128) void gather_proj_kernel(
    const float* __restrict__ value, const int* __restrict__ idxb,
    const float* __restrict__ Wmat, int wt_transposed,
    const float* __restrict__ bout, float* __restrict__ outp)
{
    __shared__ float o[128];
    const int blk = blockIdx.x;
    const int n = blk >> 12;
    const int q = blk & 4095;
    const int d = threadIdx.x;

    const float CNT[4] = {1.0f, 2.0f, 2.0f, 1.0f};

    float acc = 0.0f;
    const int* ib = idxb + (size_t)(n * LEN + q) * 16;
    for (int t = 0; t < 4; ++t) {
        const float* __restrict__ Vf = value + (size_t)((n * NFR + t) * FRAME) * DCH;
        for (int pp = 0; pp < 4; ++pp) {
            int sel = ib[t * 4 + pp];
            int oh_s = sel & 31, ow_s = sel >> 5;
            if (oh_s >= 2 && oh_s <= 29 && ow_s >= 2 && ow_s <= 28) {
                const float* base = Vf + (size_t)((oh_s - 2) * 32 + (ow_s - 2)) * DCH + d;
                #pragma unroll
                for (int dyy = 0; dyy < 4; ++dyy)
                    #pragma unroll
                    for (int dxx = 0; dxx < 4; ++dxx)
                        acc = fmaf(CNT[dyy] * CNT[dxx] * 0.25f,
                                   base[(size_t)(dyy * 32 + dxx) * DCH], acc);
            } else {
                #pragma unroll
                for (int j = 0; j < 9; ++j) {
                    const int shift = (j / 3 - 1) * 32 + (j % 3 - 1);
                    int r = sel + shift;
                    r = r < 0 ? 0 : (r > 961 ? 961 : r);
                    int ow = r >> 5, oh = r & 31;
                    #pragma unroll
                    for (int dy = 0; dy < 2; ++dy)
                        #pragma unroll
                        for (int dx = 0; dx < 2; ++dx) {
                            int yi = oh - 1 + dy, xi = ow - 1 + dx;
                            if (yi >= 0 && xi >= 0)   // upper bounds always hold
                                acc += 0.25f * Vf[(size_t)(yi * 32 + xi) * DCH + d];
                        }
                }
            }
        }
    }
    o[d] = acc * (1.0f / 144.0f);   // aw = 1/(NL*P9); bilinear 0.25 folded above
    __syncthreads();
    float res = bout[d];
    if (wt_transposed) {
        #pragma unroll 8
        for (int c = 0; c < 128; ++c) res = fmaf(o[c], Wmat[c * 128 + d], res);
    } else {
        #pragma unroll 8
        for (int c = 0; c < 128; ++c) res = fmaf(o[c], Wmat[d * 128 + c], res);
    }
    outp[(size_t)(n * LEN + q) * DCH + d] = res;
}

// ---------------------------------------------------------------------------
extern "C" void kernel_launch(void* const* d_in, const int* in_sizes, int n_in,
                              void* d_out, int out_size, void* d_ws, size_t ws_size,
                              hipStream_t stream)
{
    const float* query = (const float*)d_in[0];
    const float* value = (const float*)d_in[2];
    const float* W_out = (const float*)d_in[5];
    const float* b_out = (const float*)d_in[6];

    const size_t idx_bytes = (size_t)2 * LEN * NFR * 4 * sizeof(int);   // 512 KB

    int*   idxb = (int*)d_ws;
    float* WT   = (float*)((char*)d_ws + idx_bytes);
    const bool have_wt = ws_size >= idx_bytes + (size_t)128 * 128 * sizeof(float);

    float* outp  = (float*)d_out;                               // (2,4096,128)
    float* slout = (float*)d_out + (size_t)2 * LEN * DCH;       // (2,4096,1,4,36,2)

    if (have_wt)
        hipLaunchKernelGGL(wt_kernel, dim3(64), dim3(256), 0, stream, W_out, WT);

    hipLaunchKernelGGL(corr_topk_kernel, dim3(512), dim3(512), 0, stream,
                       query, value, idxb);

    hipLaunchKernelGGL(sloc_kernel, dim3(4608), dim3(256), 0, stream, idxb, slout);

    hipLaunchKernelGGL(gather_proj_kernel, dim3(2 * LEN), dim3(128), 0, stream,
                       value, idxb,
                       have_wt ? WT : W_out, have_wt ? 1 : 0,
                       b_out, outp);
}

// Round 7
// 627.909 us; speedup vs baseline: 1.7584x; 1.7584x over previous
//
#include <hip/hip_runtime.h>

#define LEN 4096
#define FRAME 1024
#define DCH 128
#define NFR 4

// ---------------------------------------------------------------------------
// Kernel 1: fused S-GEMM (S = Q_tq * V_tk^T, K=128) + 9-point band-sum
//           + running top-4.  (ROUND-1 VERBATIM: proven pass, 590 us.)
// grid: 256 = n(2) * tq(4) * tk(4) * ablock(8); block: 512 threads.
// ---------------------------------------------------------------------------
__global__ __launch_bounds__(512, 2) void corr_topk_kernel(
    const float* __restrict__ query,
    const float* __restrict__ value,
    int* __restrict__ idx_out)
{
    __shared__ float Ssl[192 * 64];        // S slab: 192 a' rows x 64 b' cols (2 b-rows)
    __shared__ float corrw[128 * 4 * 32];  // corr window: 128 a x 4 b-row slots x 32 wb
    __shared__ float Qc[192 * 33];         // Q K-chunk (padded)
    __shared__ float Vc[64 * 33];          // V K-chunk (padded)

    const int wg = blockIdx.x;
    const int n  = wg >> 7;
    const int tq = (wg >> 5) & 3;
    const int tk = (wg >> 3) & 3;
    const int ab = wg & 7;
    const int A0 = ab * 128;

    const float* __restrict__ Qf = query + (size_t)((n * NFR + tq) * FRAME) * DCH;
    const float* __restrict__ Vf = value + (size_t)((n * NFR + tk) * FRAME) * DCH;

    const int tid = threadIdx.x;
    const int ag = tid >> 4;   // 0..31 : GEMM a'-group (6 rows each)
    const int bg = tid & 15;   // 0..15 : GEMM b'-group (4 cols each)
    const int g  = tid >> 5;   // 0..15 : accumulate a-group (8 a each)
    const int wb = tid & 31;   // 0..31 : accumulate b-column (lane-fast)

    for (int i = tid; i < 128 * 4 * 32; i += 512) corrw[i] = 0.0f;

    // per-a top-4 state (threads 0..127; a = tid)
    float tv0 = -3.402823466e38f, tv1 = tv0, tv2 = tv0, tv3 = tv0;
    int   ti0 = 0x7fffffff, ti1 = 0x7fffffff, ti2 = 0x7fffffff, ti3 = 0x7fffffff;

#define TOPK_INSERT(vv, bb)                                                     \
    {                                                                           \
        float v_ = (vv); int b_ = (bb);                                         \
        bool c0 = (v_ > tv0) || (v_ == tv0 && b_ < ti0);                        \
        bool c1 = (v_ > tv1) || (v_ == tv1 && b_ < ti1);                        \
        bool c2 = (v_ > tv2) || (v_ == tv2 && b_ < ti2);                        \
        bool c3 = (v_ > tv3) || (v_ == tv3 && b_ < ti3);                        \
        tv3 = c3 ? (c2 ? tv2 : v_) : tv3; ti3 = c3 ? (c2 ? ti2 : b_) : ti3;     \
        tv2 = c2 ? (c1 ? tv1 : v_) : tv2; ti2 = c2 ? (c1 ? ti1 : b_) : ti2;     \
        tv1 = c1 ? (c0 ? tv0 : v_) : tv1; ti1 = c1 ? (c0 ? ti0 : b_) : ti1;     \
        tv0 = c0 ? v_ : tv0;              ti0 = c0 ? b_ : ti0;                  \
    }

    __syncthreads();

    for (int p = 0; p < 16; ++p) {
        // ---------------- S slab GEMM: rows A0-32 .. A0+159 vs b' rows [64p, 64p+64)
        float acc[6][4];
        #pragma unroll
        for (int i = 0; i < 6; ++i)
            #pragma unroll
            for (int j = 0; j < 4; ++j) acc[i][j] = 0.0f;

        for (int kc = 0; kc < 4; ++kc) {
            __syncthreads();
            // load Q chunk: 192 rows x 32 k (zero-fill out-of-frame rows)
            #pragma unroll
            for (int i = 0; i < 3; ++i) {
                int v = tid + i * 512;          // 0..1535
                int row = v >> 3;
                int kq = (v & 7) * 4;
                int agl = A0 - 32 + row;
                float4 q4 = make_float4(0.f, 0.f, 0.f, 0.f);
                if (agl >= 0 && agl < FRAME)
                    q4 = *reinterpret_cast<const float4*>(Qf + (size_t)agl * DCH + kc * 32 + kq);
                float* dst = &Qc[row * 33 + kq];
                dst[0] = q4.x; dst[1] = q4.y; dst[2] = q4.z; dst[3] = q4.w;
            }
            {   // load V chunk: 64 rows x 32 k
                int row = tid >> 3;
                int kq = (tid & 7) * 4;
                float4 v4 = *reinterpret_cast<const float4*>(Vf + (size_t)(p * 64 + row) * DCH + kc * 32 + kq);
                float* dst = &Vc[row * 33 + kq];
                dst[0] = v4.x; dst[1] = v4.y; dst[2] = v4.z; dst[3] = v4.w;
            }
            __syncthreads();

            float pacc[6][4];
            #pragma unroll
            for (int i = 0; i < 6; ++i)
                #pragma unroll
                for (int j = 0; j < 4; ++j) pacc[i][j] = 0.0f;

            #pragma unroll 8
            for (int k = 0; k < 32; ++k) {
                float qv[6], vv[4];
                #pragma unroll
                for (int i = 0; i < 6; ++i) qv[i] = Qc[(ag * 6 + i) * 33 + k];
                #pragma unroll
                for (int j = 0; j < 4; ++j) vv[j] = Vc[(bg * 4 + j) * 33 + k];
                #pragma unroll
                for (int i = 0; i < 6; ++i)
                    #pragma unroll
                    for (int j = 0; j < 4; ++j)
                        pacc[i][j] = fmaf(qv[i], vv[j], pacc[i][j]);
            }
            #pragma unroll
            for (int i = 0; i < 6; ++i)
                #pragma unroll
                for (int j = 0; j < 4; ++j) acc[i][j] += pacc[i][j];  // chunked partials
        }
        __syncthreads();
        #pragma unroll
        for (int i = 0; i < 6; ++i)
            #pragma unroll
            for (int j = 0; j < 4; ++j)
                Ssl[(ag * 6 + i) * 64 + (bg * 4 + j)] = acc[i][j];
        __syncthreads();

        // ---------------- band-sum accumulate into corr window (rows 2p-1 .. 2p+2)
        #pragma unroll
        for (int hh = 0; hh < 4; ++hh) {
            int hb = 2 * p - 1 + hh;
            if (hb < 0 || hb >= 32) continue;
            int slot = hb & 3;
            #pragma unroll
            for (int ai = 0; ai < 8; ++ai) {
                int local = g * 8 + ai;
                int wa = local & 31;
                int ha = ab * 4 + (local >> 5);
                float sum = 0.0f;
                #pragma unroll
                for (int hp = 0; hp < 2; ++hp) {
                    const int di = hp + 1 - hh;        // compile-time per (hh,hp)
                    if (di < -1 || di > 1) continue;
                    if ((unsigned)(ha + di) >= 32u) continue;   // q-side row mask
                    #pragma unroll
                    for (int dj = -1; dj <= 1; ++dj) {
                        if ((unsigned)(wa + dj) >= 32u) continue;  // q-side col mask
                        int wbp = wb + dj;
                        if ((unsigned)wbp >= 32u) continue;        // k-side col mask
                        sum += Ssl[(local + 32 + di * 32 + dj) * 64 + hp * 32 + wbp];
                    }
                }
                corrw[local * 128 + slot * 32 + wb] += sum;
            }
        }
        __syncthreads();

        // ---------------- finalize complete rows 2p-1, 2p : top-4 update
        #pragma unroll
        for (int f = 0; f < 2; ++f) {
            int hb = 2 * p - 1 + f;
            if (hb < 0) continue;
            if (tid < 128) {
                int slot = hb & 3;
                for (int s = 0; s < 32; ++s) {
                    int w2 = (tid + s) & 31;   // staggered: bank-conflict-free
                    float v = corrw[tid * 128 + slot * 32 + w2];
                    TOPK_INSERT(v, hb * 32 + w2);
                }
            }
        }
        __syncthreads();
        // zero the two finalized slots (become rows 2p+3, 2p+4)
        for (int f = 0; f < 2; ++f) {
            int hb = 2 * p - 1 + f;
            if (hb < 0) continue;
            int slot = hb & 3;
            for (int i = tid; i < 128 * 32; i += 512)
                corrw[(i >> 5) * 128 + slot * 32 + (i & 31)] = 0.0f;
        }
        __syncthreads();
    }

    // finalize last row (31) and emit indices
    if (tid < 128) {
        const int hb = 31, slot = 3;
        for (int s = 0; s < 32; ++s) {
            int w2 = (tid + s) & 31;
            float v = corrw[tid * 128 + slot * 32 + w2];
            TOPK_INSERT(v, hb * 32 + w2);
        }
        int q = tq * FRAME + A0 + tid;
        int base = ((n * LEN + q) * NFR + tk) * 4;
        idx_out[base + 0] = ti0;
        idx_out[base + 1] = ti1;
        idx_out[base + 2] = ti2;
        idx_out[base + 3] = ti3;
    }
#undef TOPK_INSERT
}

// ---------------------------------------------------------------------------
// Kernel 2: W_out transpose (proven).
// ---------------------------------------------------------------------------
__global__ void wt_kernel(const float* __restrict__ W, float* __restrict__ WT)
{
    int i = blockIdx.x * 256 + threadIdx.x;   // 16384
    int c = i >> 7, dd = i & 127;
    WT[c * 128 + dd] = W[dd * 128 + c];
}

// ---------------------------------------------------------------------------
// Kernel 3: sampling_locations (proven).
// ---------------------------------------------------------------------------
__global__ void sloc_kernel(const int* __restrict__ idxb, float* __restrict__ slout)
{
    int gid = blockIdx.x * 256 + threadIdx.x;     // < 1179648
    int pp = gid & 3;
    int t1 = gid >> 2;
    int j  = t1 % 9;
    int t2 = t1 / 9;
    int t  = t2 & 3;
    int q  = (t2 >> 2) & 4095;
    int n  = t2 >> 14;
    int sel = idxb[((n * LEN + q) * NFR + t) * 4 + pp];
    int shift = (j / 3 - 1) * 32 + (j % 3 - 1);
    int r = sel + shift;
    r = r < 0 ? 0 : (r > 961 ? 961 : r);
    float2 loc = make_float2((float)(r >> 5) * (1.0f / 32.0f),
                             (float)(r & 31) * (1.0f / 32.0f));
    *reinterpret_cast<float2*>(slout + (size_t)gid * 2) = loc;
}

// ---------------------------------------------------------------------------
// Kernel 4: gather + bilinear (weights exactly 0.25) + fused projection,
// with interior fast path (proven in rounds 2-3). Identity block order.
// ---------------------------------------------------------------------------
__global__ __launch_bounds__(128) void gather_proj_kernel(
    const float* __restrict__ value, const int* __restrict__ idxb,
    const float* __restrict__ Wmat, int wt_transposed,
    const float* __restrict__ bout, float* __restrict__ outp)
{
    __shared__ float o[128];
    const int blk = blockIdx.x;
    const int n = blk >> 12;
    const int q = blk & 4095;
    const int d = threadIdx.x;

    const float CNT[4] = {1.0f, 2.0f, 2.0f, 1.0f};

    float acc = 0.0f;
    const int* ib = idxb + (size_t)(n * LEN + q) * 16;
    for (int t = 0; t < 4; ++t) {
        const float* __restrict__ Vf = value + (size_t)((n * NFR + t) * FRAME) * DCH;
        for (int pp = 0; pp < 4; ++pp) {
            int sel = ib[t * 4 + pp];
            int oh_s = sel & 31, ow_s = sel >> 5;
            if (oh_s >= 2 && oh_s <= 29 && ow_s >= 2 && ow_s <= 28) {
                const float* base = Vf + (size_t)((oh_s - 2) * 32 + (ow_s - 2)) * DCH + d;
                #pragma unroll
                for (int dyy = 0; dyy < 4; ++dyy)
                    #pragma unroll
                    for (int dxx = 0; dxx < 4; ++dxx)
                        acc = fmaf(CNT[dyy] * CNT[dxx] * 0.25f,
                                   base[(size_t)(dyy * 32 + dxx) * DCH], acc);
            } else {
                #pragma unroll
                for (int j = 0; j < 9; ++j) {
                    const int shift = (j / 3 - 1) * 32 + (j % 3 - 1);
                    int r = sel + shift;
                    r = r < 0 ? 0 : (r > 961 ? 961 : r);
                    int ow = r >> 5, oh = r & 31;
                    #pragma unroll
                    for (int dy = 0; dy < 2; ++dy)
                        #pragma unroll
                        for (int dx = 0; dx < 2; ++dx) {
                            int yi = oh - 1 + dy, xi = ow - 1 + dx;
                            if (yi >= 0 && xi >= 0)   // upper bounds always hold
                                acc += 0.25f * Vf[(size_t)(yi * 32 + xi) * DCH + d];
                        }
                }
            }
        }
    }
    o[d] = acc * (1.0f / 144.0f);   // aw = 1/(NL*P9); bilinear 0.25 folded above
    __syncthreads();
    float res = bout[d];
    if (wt_transposed) {
        #pragma unroll 8
        for (int c = 0; c < 128; ++c) res = fmaf(o[c], Wmat[c * 128 + d], res);
    } else {
        #pragma unroll 8
        for (int c = 0; c < 128; ++c) res = fmaf(o[c], Wmat[d * 128 + c], res);
    }
    outp[(size_t)(n * LEN + q) * DCH + d] = res;
}

// ---------------------------------------------------------------------------
extern "C" void kernel_launch(void* const* d_in, const int* in_sizes, int n_in,
                              void* d_out, int out_size, void* d_ws, size_t ws_size,
                              hipStream_t stream)
{
    const float* query = (const float*)d_in[0];
    const float* value = (const float*)d_in[2];
    const float* W_out = (const float*)d_in[5];
    const float* b_out = (const float*)d_in[6];

    const size_t idx_bytes = (size_t)2 * LEN * NFR * 4 * sizeof(int);   // 512 KB

    int*   idxb = (int*)d_ws;
    float* WT   = (float*)((char*)d_ws + idx_bytes);
    const bool have_wt = ws_size >= idx_bytes + (size_t)128 * 128 * sizeof(float);

    float* outp  = (float*)d_out;                               // (2,4096,128)
    float* slout = (float*)d_out + (size_t)2 * LEN * DCH;       // (2,4096,1,4,36,2)

    if (have_wt)
        hipLaunchKernelGGL(wt_kernel, dim3(64), dim3(256), 0, stream, W_out, WT);

    hipLaunchKernelGGL(corr_topk_kernel, dim3(256), dim3(512), 0, stream,
                       query, value, idxb);

    hipLaunchKernelGGL(sloc_kernel, dim3(4608), dim3(256), 0, stream, idxb, slout);

    hipLaunchKernelGGL(gather_proj_kernel, dim3(2 * LEN), dim3(128), 0, stream,
                       value, idxb,
                       have_wt ? WT : W_out, have_wt ? 1 : 0,
                       b_out, outp);
}

// Round 8
// 576.466 us; speedup vs baseline: 1.9153x; 1.0892x over previous
//
#include <hip/hip_runtime.h>

#define LEN 4096
#define FRAME 1024
#define DCH 128
#define NFR 4

// ---------------------------------------------------------------------------
// Kernel 1: fused S-GEMM (S = Q_tq * V_tk^T, K=128) + 9-point band-sum
//           + running top-4.  Round-7 structure; GEMM inner loop re-tiled:
//           k-major LDS (Qc[k][row], Vc[k][col]) -> vector ds_read (3xb64 Q,
//           1xb128 V per k) + register prefetch of next k-chunk.
// grid: 256 = n(2) * tq(4) * tk(4) * ablock(8); block: 512 threads.
// LDS: Ssl 48K + corrw 64K + Qc 24.5K + Vc 8.5K = 145 KB -> 1 block/CU.
// ---------------------------------------------------------------------------
__global__ __launch_bounds__(512, 2) void corr_topk_kernel(
    const float* __restrict__ query,
    const float* __restrict__ value,
    int* __restrict__ idx_out)
{
    __shared__ float Ssl[192 * 64];        // S slab: 192 a' rows x 64 b' cols
    __shared__ float corrw[128 * 4 * 32];  // corr window: 128 a x 4 slots x 32 wb
    __shared__ float Qc[32 * 196];         // k-major Q chunk: [k][row], pad 196
    __shared__ float Vc[32 * 68];          // k-major V chunk: [k][col], pad 68

    const int wg = blockIdx.x;
    const int n  = wg >> 7;
    const int tq = (wg >> 5) & 3;
    const int tk = (wg >> 3) & 3;
    const int ab = wg & 7;
    const int A0 = ab * 128;

    const float* __restrict__ Qf = query + (size_t)((n * NFR + tq) * FRAME) * DCH;
    const float* __restrict__ Vf = value + (size_t)((n * NFR + tk) * FRAME) * DCH;

    const int tid = threadIdx.x;
    const int ag = tid >> 4;   // 0..31 : GEMM a'-group (6 rows each)
    const int bg = tid & 15;   // 0..15 : GEMM b'-group (4 cols each)
    const int g  = tid >> 5;   // 0..15 : accumulate a-group (8 a each)
    const int wb = tid & 31;   // 0..31 : accumulate b-column (lane-fast)

    // staging roles (fixed per thread):
    // Q: 3 float4 slots; V: 1 float4.
    int qrow[3], qk4[3]; bool qok[3];
    const float* qsrc[3];
    #pragma unroll
    for (int s = 0; s < 3; ++s) {
        int i = tid + s * 512;             // 0..1535
        qrow[s] = i >> 3;                  // 0..191
        qk4[s]  = (i & 7) * 4;             // 0,4,..,28
        int agl = A0 - 32 + qrow[s];
        qok[s]  = (unsigned)agl < (unsigned)FRAME;
        qsrc[s] = Qf + (size_t)(qok[s] ? agl : 0) * DCH + qk4[s];
    }
    const int vrow = tid >> 3;             // 0..63
    const int vk4  = (tid & 7) * 4;        // 0,4,..,28
    const float* vsrc = Vf + (size_t)vrow * DCH + vk4;

    for (int i = tid; i < 128 * 4 * 32; i += 512) corrw[i] = 0.0f;

    // per-a top-4 state (threads 0..127; a = tid)
    float tv0 = -3.402823466e38f, tv1 = tv0, tv2 = tv0, tv3 = tv0;
    int   ti0 = 0x7fffffff, ti1 = 0x7fffffff, ti2 = 0x7fffffff, ti3 = 0x7fffffff;

#define TOPK_INSERT(vv, bb)                                                     \
    {                                                                           \
        float v_ = (vv); int b_ = (bb);                                         \
        bool c0 = (v_ > tv0) || (v_ == tv0 && b_ < ti0);                        \
        bool c1 = (v_ > tv1) || (v_ == tv1 && b_ < ti1);                        \
        bool c2 = (v_ > tv2) || (v_ == tv2 && b_ < ti2);                        \
        bool c3 = (v_ > tv3) || (v_ == tv3 && b_ < ti3);                        \
        tv3 = c3 ? (c2 ? tv2 : v_) : tv3; ti3 = c3 ? (c2 ? ti2 : b_) : ti3;     \
        tv2 = c2 ? (c1 ? tv1 : v_) : tv2; ti2 = c2 ? (c1 ? ti1 : b_) : ti2;     \
        tv1 = c1 ? (c0 ? tv0 : v_) : tv1; ti1 = c1 ? (c0 ? ti0 : b_) : ti1;     \
        tv0 = c0 ? v_ : tv0;              ti0 = c0 ? b_ : ti0;                  \
    }

    __syncthreads();

    for (int p = 0; p < 16; ++p) {
        // ---------------- S slab GEMM: rows A0-32 .. A0+159 vs b' [64p, 64p+64)
        float acc[6][4];
        #pragma unroll
        for (int i = 0; i < 6; ++i)
            #pragma unroll
            for (int j = 0; j < 4; ++j) acc[i][j] = 0.0f;

        // preload chunk kc=0 into registers
        float4 gq[3], gv;
        #pragma unroll
        for (int s = 0; s < 3; ++s)
            gq[s] = qok[s] ? *reinterpret_cast<const float4*>(qsrc[s])
                           : make_float4(0.f, 0.f, 0.f, 0.f);
        gv = *reinterpret_cast<const float4*>(vsrc + (size_t)(p * 64) * DCH);

        for (int kc = 0; kc < 4; ++kc) {
            __syncthreads();   // previous chunk's compute done (Qc/Vc free)
            // write staged registers -> k-major LDS
            #pragma unroll
            for (int s = 0; s < 3; ++s) {
                Qc[(qk4[s] + 0) * 196 + qrow[s]] = gq[s].x;
                Qc[(qk4[s] + 1) * 196 + qrow[s]] = gq[s].y;
                Qc[(qk4[s] + 2) * 196 + qrow[s]] = gq[s].z;
                Qc[(qk4[s] + 3) * 196 + qrow[s]] = gq[s].w;
            }
            Vc[(vk4 + 0) * 68 + vrow] = gv.x;
            Vc[(vk4 + 1) * 68 + vrow] = gv.y;
            Vc[(vk4 + 2) * 68 + vrow] = gv.z;
            Vc[(vk4 + 3) * 68 + vrow] = gv.w;
            __syncthreads();   // writes visible

            // prefetch next chunk (hides global latency under compute)
            if (kc < 3) {
                const int off = (kc + 1) * 32;
                #pragma unroll
                for (int s = 0; s < 3; ++s)
                    if (qok[s]) gq[s] = *reinterpret_cast<const float4*>(qsrc[s] + off);
                gv = *reinterpret_cast<const float4*>(vsrc + (size_t)(p * 64) * DCH + off);
            }

            float pacc[6][4];
            #pragma unroll
            for (int i = 0; i < 6; ++i)
                #pragma unroll
                for (int j = 0; j < 4; ++j) pacc[i][j] = 0.0f;

            #pragma unroll 8
            for (int k = 0; k < 32; ++k) {
                const float* qb = &Qc[k * 196 + ag * 6];
                float2 qa = *reinterpret_cast<const float2*>(qb);
                float2 qm = *reinterpret_cast<const float2*>(qb + 2);
                float2 qc = *reinterpret_cast<const float2*>(qb + 4);
                float4 vv = *reinterpret_cast<const float4*>(&Vc[k * 68 + bg * 4]);
                float qv[6];
                qv[0] = qa.x; qv[1] = qa.y; qv[2] = qm.x;
                qv[3] = qm.y; qv[4] = qc.x; qv[5] = qc.y;
                #pragma unroll
                for (int i = 0; i < 6; ++i) {
                    pacc[i][0] = fmaf(qv[i], vv.x, pacc[i][0]);
                    pacc[i][1] = fmaf(qv[i], vv.y, pacc[i][1]);
                    pacc[i][2] = fmaf(qv[i], vv.z, pacc[i][2]);
                    pacc[i][3] = fmaf(qv[i], vv.w, pacc[i][3]);
                }
            }
            #pragma unroll
            for (int i = 0; i < 6; ++i)
                #pragma unroll
                for (int j = 0; j < 4; ++j) acc[i][j] += pacc[i][j];  // chunked partials
        }
        __syncthreads();
        #pragma unroll
        for (int i = 0; i < 6; ++i)
            #pragma unroll
            for (int j = 0; j < 4; ++j)
                Ssl[(ag * 6 + i) * 64 + (bg * 4 + j)] = acc[i][j];
        __syncthreads();

        // ---------------- band-sum accumulate into corr window (rows 2p-1 .. 2p+2)
        #pragma unroll
        for (int hh = 0; hh < 4; ++hh) {
            int hb = 2 * p - 1 + hh;
            if (hb < 0 || hb >= 32) continue;
            int slot = hb & 3;
            #pragma unroll
            for (int ai = 0; ai < 8; ++ai) {
                int local = g * 8 + ai;
                int wa = local & 31;
                int ha = ab * 4 + (local >> 5);
                float sum = 0.0f;
                #pragma unroll
                for (int hp = 0; hp < 2; ++hp) {
                    const int di = hp + 1 - hh;        // compile-time per (hh,hp)
                    if (di < -1 || di > 1) continue;
                    if ((unsigned)(ha + di) >= 32u) continue;   // q-side row mask
                    #pragma unroll
                    for (int dj = -1; dj <= 1; ++dj) {
                        if ((unsigned)(wa + dj) >= 32u) continue;  // q-side col mask
                        int wbp = wb + dj;
                        if ((unsigned)wbp >= 32u) continue;        // k-side col mask
                        sum += Ssl[(local + 32 + di * 32 + dj) * 64 + hp * 32 + wbp];
                    }
                }
                corrw[local * 128 + slot * 32 + wb] += sum;
            }
        }
        __syncthreads();

        // ---------------- finalize complete rows 2p-1, 2p : top-4 update
        #pragma unroll
        for (int f = 0; f < 2; ++f) {
            int hb = 2 * p - 1 + f;
            if (hb < 0) continue;
            if (tid < 128) {
                int slot = hb & 3;
                for (int s = 0; s < 32; ++s) {
                    int w2 = (tid + s) & 31;   // staggered: bank-conflict-free
                    float v = corrw[tid * 128 + slot * 32 + w2];
                    TOPK_INSERT(v, hb * 32 + w2);
                }
            }
        }
        __syncthreads();
        // zero the two finalized slots (become rows 2p+3, 2p+4)
        for (int f = 0; f < 2; ++f) {
            int hb = 2 * p - 1 + f;
            if (hb < 0) continue;
            int slot = hb & 3;
            for (int i = tid; i < 128 * 32; i += 512)
                corrw[(i >> 5) * 128 + slot * 32 + (i & 31)] = 0.0f;
        }
        __syncthreads();
    }

    // finalize last row (31) and emit indices
    if (tid < 128) {
        const int hb = 31, slot = 3;
        for (int s = 0; s < 32; ++s) {
            int w2 = (tid + s) & 31;
            float v = corrw[tid * 128 + slot * 32 + w2];
            TOPK_INSERT(v, hb * 32 + w2);
        }
        int q = tq * FRAME + A0 + tid;
        int base = ((n * LEN + q) * NFR + tk) * 4;
        idx_out[base + 0] = ti0;
        idx_out[base + 1] = ti1;
        idx_out[base + 2] = ti2;
        idx_out[base + 3] = ti3;
    }
#undef TOPK_INSERT
}

// ---------------------------------------------------------------------------
// Kernel 2: W_out transpose (proven).
// ---------------------------------------------------------------------------
__global__ void wt_kernel(const float* __restrict__ W, float* __restrict__ WT)
{
    int i = blockIdx.x * 256 + threadIdx.x;   // 16384
    int c = i >> 7, dd = i & 127;
    WT[c * 128 + dd] = W[dd * 128 + c];
}

// ---------------------------------------------------------------------------
// Kernel 3: sampling_locations (proven).
// ---------------------------------------------------------------------------
__global__ void sloc_kernel(const int* __restrict__ idxb, float* __restrict__ slout)
{
    int gid = blockIdx.x * 256 + threadIdx.x;     // < 1179648
    int pp = gid & 3;
    int t1 = gid >> 2;
    int j  = t1 % 9;
    int t2 = t1 / 9;
    int t  = t2 & 3;
    int q  = (t2 >> 2) & 4095;
    int n  = t2 >> 14;
    int sel = idxb[((n * LEN + q) * NFR + t) * 4 + pp];
    int shift = (j / 3 - 1) * 32 + (j % 3 - 1);
    int r = sel + shift;
    r = r < 0 ? 0 : (r > 961 ? 961 : r);
    float2 loc = make_float2((float)(r >> 5) * (1.0f / 32.0f),
                             (float)(r & 31) * (1.0f / 32.0f));
    *reinterpret_cast<float2*>(slout + (size_t)gid * 2) = loc;
}

// ---------------------------------------------------------------------------
// Kernel 4: gather + bilinear (weights exactly 0.25) + fused projection,
// with interior fast path (proven). Identity block order.
// ---------------------------------------------------------------------------
__global__ __launch_bounds__(128) void gather_proj_kernel(
    const float* __restrict__ value, const int* __restrict__ idxb,
    const float* __restrict__ Wmat, int wt_transposed,
    const float* __restrict__ bout, float* __restrict__ outp)
{
    __shared__ float o[128];
    const int blk = blockIdx.x;
    const int n = blk >> 12;
    const int q = blk & 4095;
    const int d = threadIdx.x;

    const float CNT[4] = {1.0f, 2.0f, 2.0f, 1.0f};

    float acc = 0.0f;
    const int* ib = idxb + (size_t)(n * LEN + q) * 16;
    for (int t = 0; t < 4; ++t) {
        const float* __restrict__ Vf = value + (size_t)((n * NFR + t) * FRAME) * DCH;
        for (int pp = 0; pp < 4; ++pp) {
            int sel = ib[t * 4 + pp];
            int oh_s = sel & 31, ow_s = sel >> 5;
            if (oh_s >= 2 && oh_s <= 29 && ow_s >= 2 && ow_s <= 28) {
                const float* base = Vf + (size_t)((oh_s - 2) * 32 + (ow_s - 2)) * DCH + d;
                #pragma unroll
                for (int dyy = 0; dyy < 4; ++dyy)
                    #pragma unroll
                    for (int dxx = 0; dxx < 4; ++dxx)
                        acc = fmaf(CNT[dyy] * CNT[dxx] * 0.25f,
                                   base[(size_t)(dyy * 32 + dxx) * DCH], acc);
            } else {
                #pragma unroll
                for (int j = 0; j < 9; ++j) {
                    const int shift = (j / 3 - 1) * 32 + (j % 3 - 1);
                    int r = sel + shift;
                    r = r < 0 ? 0 : (r > 961 ? 961 : r);
                    int ow = r >> 5, oh = r & 31;
                    #pragma unroll
                    for (int dy = 0; dy < 2; ++dy)
                        #pragma unroll
                        for (int dx = 0; dx < 2; ++dx) {
                            int yi = oh - 1 + dy, xi = ow - 1 + dx;
                            if (yi >= 0 && xi >= 0)   // upper bounds always hold
                                acc += 0.25f * Vf[(size_t)(yi * 32 + xi) * DCH + d];
                        }
                }
            }
        }
    }
    o[d] = acc * (1.0f / 144.0f);   // aw = 1/(NL*P9); bilinear 0.25 folded above
    __syncthreads();
    float res = bout[d];
    if (wt_transposed) {
        #pragma unroll 8
        for (int c = 0; c < 128; ++c) res = fmaf(o[c], Wmat[c * 128 + d], res);
    } else {
        #pragma unroll 8
        for (int c = 0; c < 128; ++c) res = fmaf(o[c], Wmat[d * 128 + c], res);
    }
    outp[(size_t)(n * LEN + q) * DCH + d] = res;
}

// ---------------------------------------------------------------------------
extern "C" void kernel_launch(void* const* d_in, const int* in_sizes, int n_in,
                              void* d_out, int out_size, void* d_ws, size_t ws_size,
                              hipStream_t stream)
{
    const float* query = (const float*)d_in[0];
    const float* value = (const float*)d_in[2];
    const float* W_out = (const float*)d_in[5];
    const float* b_out = (const float*)d_in[6];

    const size_t idx_bytes = (size_t)2 * LEN * NFR * 4 * sizeof(int);   // 512 KB

    int*   idxb = (int*)d_ws;
    float* WT   = (float*)((char*)d_ws + idx_bytes);
    const bool have_wt = ws_size >= idx_bytes + (size_t)128 * 128 * sizeof(float);

    float* outp  = (float*)d_out;                               // (2,4096,128)
    float* slout = (float*)d_out + (size_t)2 * LEN * DCH;       // (2,4096,1,4,36,2)

    if (have_wt)
        hipLaunchKernelGGL(wt_kernel, dim3(64), dim3(256), 0, stream, W_out, WT);

    hipLaunchKernelGGL(corr_topk_kernel, dim3(256), dim3(512), 0, stream,
                       query, value, idxb);

    hipLaunchKernelGGL(sloc_kernel, dim3(4608), dim3(256), 0, stream, idxb, slout);

    hipLaunchKernelGGL(gather_proj_kernel, dim3(2 * LEN), dim3(128), 0, stream,
                       value, idxb,
                       have_wt ? WT : W_out, have_wt ? 1 : 0,
                       b_out, outp);
}

// Round 9
// 408.263 us; speedup vs baseline: 2.7044x; 1.4120x over previous
//
#include <hip/hip_runtime.h>

#define LEN 4096
#define FRAME 1024
#define DCH 128
#define NFR 4

// ---------------------------------------------------------------------------
// Kernel 1: fused S-GEMM (S = Q_tq * V_tk^T, K=128) + 9-point band-sum
//           + running top-4.
// Round-8 GEMM (k-major LDS, 6x4 tile, identical accumulation order) +
// round-2/3-proven register corr window (cr[4][8], wq octets) +
// double-buffered k-chunks -> 5 barriers per p-slab (was ~12).
// grid: 256 = n(2)*tq(4)*tk(4)*ab(8); block 512. LDS 115 KB, 1 block/CU.
// ---------------------------------------------------------------------------
__global__ __launch_bounds__(512, 2) void corr_topk_kernel(
    const float* __restrict__ query,
    const float* __restrict__ value,
    int* __restrict__ idx_out)
{
    __shared__ float Ssl[192 * 65];      // 49,920 B (stride 65: staggered banks)
    __shared__ float Qc[2][32 * 196];    // 50,176 B  k-major [k][row], dbuf
    __shared__ float Vc[2][32 * 68];     // 17,408 B  k-major [k][col], dbuf

    const int wg = blockIdx.x;
    const int n  = wg >> 7;
    const int tq = (wg >> 5) & 3;
    const int tk = (wg >> 3) & 3;
    const int ab = wg & 7;
    const int A0 = ab * 128;

    const float* __restrict__ Qf = query + (size_t)((n * NFR + tq) * FRAME) * DCH;
    const float* __restrict__ Vf = value + (size_t)((n * NFR + tk) * FRAME) * DCH;

    const int tid = threadIdx.x;
    const int ag = tid >> 4;   // 0..31 : GEMM a'-group (6 rows each)
    const int bg = tid & 15;   // 0..15 : GEMM b'-group (4 cols each)

    // band-sum / top-k mapping (round-2-proven shape: 128 a-rows, 4 wq octets)
    const int a_loc = tid >> 2;            // 0..127
    const int wq    = tid & 3;             // wb octet: wb = wq*8 + u
    const int wa    = a_loc & 31;
    const int ha    = ab * 4 + (a_loc >> 5);

    // staging roles (fixed per thread): Q 3 float4 slots, V 1 float4
    int qrow[3], qk4[3]; bool qok[3];
    const float* qsrc[3];
    #pragma unroll
    for (int s = 0; s < 3; ++s) {
        int i = tid + s * 512;             // 0..1535
        qrow[s] = i >> 3;                  // 0..191
        qk4[s]  = (i & 7) * 4;             // 0,4,..,28
        int agl = A0 - 32 + qrow[s];
        qok[s]  = (unsigned)agl < (unsigned)FRAME;
        qsrc[s] = Qf + (size_t)(qok[s] ? agl : 0) * DCH + qk4[s];
    }
    const int vrow = tid >> 3;             // 0..63
    const int vk4  = (tid & 7) * 4;        // 0,4,..,28
    const float* vsrc = Vf + (size_t)vrow * DCH + vk4;

    float cr[32];
    #pragma unroll
    for (int i = 0; i < 32; ++i) cr[i] = 0.0f;

    float tv0 = -3.402823466e38f, tv1 = tv0, tv2 = tv0, tv3 = tv0;
    int   ti0 = 0x7fffffff, ti1 = ti0, ti2 = ti0, ti3 = ti0;

#define TOPK_INSERT(vv, bb)                                                     \
    {                                                                           \
        float v_ = (vv); int b_ = (bb);                                         \
        bool c0 = (v_ > tv0) || (v_ == tv0 && b_ < ti0);                        \
        bool c1 = (v_ > tv1) || (v_ == tv1 && b_ < ti1);                        \
        bool c2 = (v_ > tv2) || (v_ == tv2 && b_ < ti2);                        \
        bool c3 = (v_ > tv3) || (v_ == tv3 && b_ < ti3);                        \
        tv3 = c3 ? (c2 ? tv2 : v_) : tv3; ti3 = c3 ? (c2 ? ti2 : b_) : ti3;     \
        tv2 = c2 ? (c1 ? tv1 : v_) : tv2; ti2 = c2 ? (c1 ? ti1 : b_) : ti2;     \
        tv1 = c1 ? (c0 ? tv0 : v_) : tv1; ti1 = c1 ? (c0 ? ti0 : b_) : ti1;     \
        tv0 = c0 ? v_ : tv0;              ti0 = c0 ? b_ : ti0;                  \
    }

// round-2-proven band accumulate: term (SLOT, S-row-pair HP, row-shift DI)
#define ACC_TERM(SLOT, HP, DI) do {                                             \
    if ((unsigned)(ha + (DI)) < 32u) {                                          \
        const float* Sr = &Ssl[(a_loc + 32 + (DI) * 32) * 65 + (HP) * 32 + wq * 8]; \
        _Pragma("unroll")                                                       \
        for (int u = 0; u < 8; ++u) {                                           \
            float s = Sr[u];                                                    \
            if ((wa > 0)  && ((u > 0) || (wq > 0))) s += Sr[u - 66];            \
            if ((wa < 31) && ((u < 7) || (wq < 3))) s += Sr[u + 66];            \
            cr[(SLOT) * 8 + u] += s;                                            \
        }                                                                       \
    }                                                                           \
} while (0)

#define FINALIZE_ROW(HB, SLOT) do {                                             \
    const int hbg_ = (HB);                                                      \
    _Pragma("unroll")                                                           \
    for (int u = 0; u < 8; ++u) {                                               \
        TOPK_INSERT(cr[(SLOT) * 8 + u], hbg_ * 32 + wq * 8 + u);                \
        cr[(SLOT) * 8 + u] = 0.0f;                                              \
    }                                                                           \
} while (0)

#define STAGE_WRITE(BUF) do {                                                   \
    _Pragma("unroll")                                                           \
    for (int s = 0; s < 3; ++s) {                                               \
        Qc[BUF][(qk4[s] + 0) * 196 + qrow[s]] = gq[s].x;                        \
        Qc[BUF][(qk4[s] + 1) * 196 + qrow[s]] = gq[s].y;                        \
        Qc[BUF][(qk4[s] + 2) * 196 + qrow[s]] = gq[s].z;                        \
        Qc[BUF][(qk4[s] + 3) * 196 + qrow[s]] = gq[s].w;                        \
    }                                                                           \
    Vc[BUF][(vk4 + 0) * 68 + vrow] = gv.x;                                      \
    Vc[BUF][(vk4 + 1) * 68 + vrow] = gv.y;                                      \
    Vc[BUF][(vk4 + 2) * 68 + vrow] = gv.z;                                      \
    Vc[BUF][(vk4 + 3) * 68 + vrow] = gv.w;                                      \
} while (0)

#define STAGE_LOAD(QOFF, VPTR) do {                                             \
    _Pragma("unroll")                                                           \
    for (int s = 0; s < 3; ++s)                                                 \
        if (qok[s]) gq[s] = *reinterpret_cast<const float4*>(qsrc[s] + (QOFF)); \
    gv = *reinterpret_cast<const float4*>(VPTR);                                \
} while (0)

// round-8-identical GEMM chunk (same accumulation order -> bit-identical S)
#define GEMM_CHUNK(BUF) do {                                                    \
    float pacc[6][4];                                                           \
    _Pragma("unroll")                                                           \
    for (int i = 0; i < 6; ++i)                                                 \
        _Pragma("unroll")                                                       \
        for (int j = 0; j < 4; ++j) pacc[i][j] = 0.0f;                          \
    _Pragma("unroll 8")                                                         \
    for (int k = 0; k < 32; ++k) {                                              \
        const float* qb = &Qc[BUF][k * 196 + ag * 6];                           \
        float2 qa = *reinterpret_cast<const float2*>(qb);                       \
        float2 qm = *reinterpret_cast<const float2*>(qb + 2);                   \
        float2 qe = *reinterpret_cast<const float2*>(qb + 4);                   \
        float4 vv = *reinterpret_cast<const float4*>(&Vc[BUF][k * 68 + bg * 4]);\
        float qv[6];                                                            \
        qv[0] = qa.x; qv[1] = qa.y; qv[2] = qm.x;                               \
        qv[3] = qm.y; qv[4] = qe.x; qv[5] = qe.y;                               \
        _Pragma("unroll")                                                       \
        for (int i = 0; i < 6; ++i) {                                           \
            pacc[i][0] = fmaf(qv[i], vv.x, pacc[i][0]);                         \
            pacc[i][1] = fmaf(qv[i], vv.y, pacc[i][1]);                         \
            pacc[i][2] = fmaf(qv[i], vv.z, pacc[i][2]);                         \
            pacc[i][3] = fmaf(qv[i], vv.w, pacc[i][3]);                         \
        }                                                                       \
    }                                                                           \
    _Pragma("unroll")                                                           \
    for (int i = 0; i < 6; ++i)                                                 \
        _Pragma("unroll")                                                       \
        for (int j = 0; j < 4; ++j) acc[i][j] += pacc[i][j];                    \
} while (0)

    // initial prefetch: (p=0, chunk0)
    float4 gq[3], gv;
    #pragma unroll
    for (int s = 0; s < 3; ++s) gq[s] = make_float4(0.f, 0.f, 0.f, 0.f);
    STAGE_LOAD(0, vsrc);

    for (int p = 0; p < 16; ++p) {
        const float* vp = vsrc + (size_t)(p * 64) * DCH;

        float acc[6][4];
        #pragma unroll
        for (int i = 0; i < 6; ++i)
            #pragma unroll
            for (int j = 0; j < 4; ++j) acc[i][j] = 0.0f;

        // region A: stage chunk0, prefetch chunk1
        STAGE_WRITE(0);
        STAGE_LOAD(32, vp + 32);
        __syncthreads();                             // B1: buf0 ready
        // region B: stage chunk1, prefetch chunk2, compute chunk0
        STAGE_WRITE(1);
        STAGE_LOAD(64, vp + 64);
        GEMM_CHUNK(0);
        __syncthreads();                             // B2: buf1 ready
        // region C: stage chunk2, prefetch chunk3, compute chunk1
        STAGE_WRITE(0);
        STAGE_LOAD(96, vp + 96);
        GEMM_CHUNK(1);
        __syncthreads();                             // B3: buf0 ready
        // region D: stage chunk3, prefetch (p+1,chunk0), compute chunk2
        STAGE_WRITE(1);
        {
            const int pn = (p < 15) ? p + 1 : 15;    // p=15: harmless re-read
            STAGE_LOAD(0, vsrc + (size_t)(pn * 64) * DCH);
        }
        GEMM_CHUNK(0);
        __syncthreads();                             // B4: buf1 ready
        // region E: compute chunk3, write S slab
        GEMM_CHUNK(1);
        #pragma unroll
        for (int i = 0; i < 6; ++i)
            #pragma unroll
            for (int j = 0; j < 4; ++j)
                Ssl[(ag * 6 + i) * 65 + bg * 4 + j] = acc[i][j];
        __syncthreads();                             // B5: Ssl visible

        // band-sum accumulate + finalize rows 2p-1, 2p (register window,
        // round-3-proven parity schedule)
        if (p & 1) {
            ACC_TERM(1, 0, +1);
            ACC_TERM(2, 0,  0); ACC_TERM(2, 1, +1);
            ACC_TERM(3, 0, -1); ACC_TERM(3, 1,  0);
            if (p < 15) ACC_TERM(0, 1, -1);
            FINALIZE_ROW(2 * p - 1, 1);
            FINALIZE_ROW(2 * p,     2);
        } else {
            if (p > 0) ACC_TERM(3, 0, +1);
            ACC_TERM(0, 0,  0); ACC_TERM(0, 1, +1);
            ACC_TERM(1, 0, -1); ACC_TERM(1, 1,  0);
            ACC_TERM(2, 1, -1);
            if (p > 0) FINALIZE_ROW(2 * p - 1, 3);
            FINALIZE_ROW(2 * p, 0);
        }
        // no end barrier: next p's B1..B4 order Ssl reads vs its rewrite
    }
    FINALIZE_ROW(31, 3);   // p=15 leaves row 31 in slot 3

    // merge top-4 across the 4 wq lanes (adjacent lanes, same wave)
    #pragma unroll
    for (int m = 1; m <= 2; m <<= 1) {
        float ov0 = __shfl_xor(tv0, m); int oi0 = __shfl_xor(ti0, m);
        float ov1 = __shfl_xor(tv1, m); int oi1 = __shfl_xor(ti1, m);
        float ov2 = __shfl_xor(tv2, m); int oi2 = __shfl_xor(ti2, m);
        float ov3 = __shfl_xor(tv3, m); int oi3 = __shfl_xor(ti3, m);
        TOPK_INSERT(ov0, oi0);
        TOPK_INSERT(ov1, oi1);
        TOPK_INSERT(ov2, oi2);
        TOPK_INSERT(ov3, oi3);
    }

    if (wq == 0) {
        const int q = tq * FRAME + A0 + a_loc;
        int4 st; st.x = ti0; st.y = ti1; st.z = ti2; st.w = ti3;
        *reinterpret_cast<int4*>(idx_out + (size_t)((n * LEN + q) * NFR + tk) * 4) = st;
    }
#undef TOPK_INSERT
#undef ACC_TERM
#undef FINALIZE_ROW
#undef STAGE_WRITE
#undef STAGE_LOAD
#undef GEMM_CHUNK
}

// ---------------------------------------------------------------------------
// Kernel 2: W_out transpose (proven).
// ---------------------------------------------------------------------------
__global__ void wt_kernel(const float* __restrict__ W, float* __restrict__ WT)
{
    int i = blockIdx.x * 256 + threadIdx.x;   // 16384
    int c = i >> 7, dd = i & 127;
    WT[c * 128 + dd] = W[dd * 128 + c];
}

// ---------------------------------------------------------------------------
// Kernel 3: sampling_locations (proven).
// ---------------------------------------------------------------------------
__global__ void sloc_kernel(const int* __restrict__ idxb, float* __restrict__ slout)
{
    int gid = blockIdx.x * 256 + threadIdx.x;     // < 1179648
    int pp = gid & 3;
    int t1 = gid >> 2;
    int j  = t1 % 9;
    int t2 = t1 / 9;
    int t  = t2 & 3;
    int q  = (t2 >> 2) & 4095;
    int n  = t2 >> 14;
    int sel = idxb[((n * LEN + q) * NFR + t) * 4 + pp];
    int shift = (j / 3 - 1) * 32 + (j % 3 - 1);
    int r = sel + shift;
    r = r < 0 ? 0 : (r > 961 ? 961 : r);
    float2 loc = make_float2((float)(r >> 5) * (1.0f / 32.0f),
                             (float)(r & 31) * (1.0f / 32.0f));
    *reinterpret_cast<float2*>(slout + (size_t)gid * 2) = loc;
}

// ---------------------------------------------------------------------------
// Kernel 4: gather + bilinear (weights exactly 0.25) + fused projection,
// with interior fast path (proven). Identity block order.
// ---------------------------------------------------------------------------
__global__ __launch_bounds__(128) void gather_proj_kernel(
    const float* __restrict__ value, const int* __restrict__ idxb,
    const float* __restrict__ Wmat, int wt_transposed,
    const float* __restrict__ bout, float* __restrict__ outp)
{
    __shared__ float o[128];
    const int blk = blockIdx.x;
    const int n = blk >> 12;
    const int q = blk & 4095;
    const int d = threadIdx.x;

    const float CNT[4] = {1.0f, 2.0f, 2.0f, 1.0f};

    float acc = 0.0f;
    const int* ib = idxb + (size_t)(n * LEN + q) * 16;
    for (int t = 0; t < 4; ++t) {
        const float* __restrict__ Vf = value + (size_t)((n * NFR + t) * FRAME) * DCH;
        for (int pp = 0; pp < 4; ++pp) {
            int sel = ib[t * 4 + pp];
            int oh_s = sel & 31, ow_s = sel >> 5;
            if (oh_s >= 2 && oh_s <= 29 && ow_s >= 2 && ow_s <= 28) {
                const float* base = Vf + (size_t)((oh_s - 2) * 32 + (ow_s - 2)) * DCH + d;
                #pragma unroll
                for (int dyy = 0; dyy < 4; ++dyy)
                    #pragma unroll
                    for (int dxx = 0; dxx < 4; ++dxx)
                        acc = fmaf(CNT[dyy] * CNT[dxx] * 0.25f,
                                   base[(size_t)(dyy * 32 + dxx) * DCH], acc);
            } else {
                #pragma unroll
                for (int j = 0; j < 9; ++j) {
                    const int shift = (j / 3 - 1) * 32 + (j % 3 - 1);
                    int r = sel + shift;
                    r = r < 0 ? 0 : (r > 961 ? 961 : r);
                    int ow = r >> 5, oh = r & 31;
                    #pragma unroll
                    for (int dy = 0; dy < 2; ++dy)
                        #pragma unroll
                        for (int dx = 0; dx < 2; ++dx) {
                            int yi = oh - 1 + dy, xi = ow - 1 + dx;
                            if (yi >= 0 && xi >= 0)   // upper bounds always hold
                                acc += 0.25f * Vf[(size_t)(yi * 32 + xi) * DCH + d];
                        }
                }
            }
        }
    }
    o[d] = acc * (1.0f / 144.0f);   // aw = 1/(NL*P9); bilinear 0.25 folded above
    __syncthreads();
    float res = bout[d];
    if (wt_transposed) {
        #pragma unroll 8
        for (int c = 0; c < 128; ++c) res = fmaf(o[c], Wmat[c * 128 + d], res);
    } else {
        #pragma unroll 8
        for (int c = 0; c < 128; ++c) res = fmaf(o[c], Wmat[d * 128 + c], res);
    }
    outp[(size_t)(n * LEN + q) * DCH + d] = res;
}

// ---------------------------------------------------------------------------
extern "C" void kernel_launch(void* const* d_in, const int* in_sizes, int n_in,
                              void* d_out, int out_size, void* d_ws, size_t ws_size,
                              hipStream_t stream)
{
    const float* query = (const float*)d_in[0];
    const float* value = (const float*)d_in[2];
    const float* W_out = (const float*)d_in[5];
    const float* b_out = (const float*)d_in[6];

    const size_t idx_bytes = (size_t)2 * LEN * NFR * 4 * sizeof(int);   // 512 KB

    int*   idxb = (int*)d_ws;
    float* WT   = (float*)((char*)d_ws + idx_bytes);
    const bool have_wt = ws_size >= idx_bytes + (size_t)128 * 128 * sizeof(float);

    float* outp  = (float*)d_out;                               // (2,4096,128)
    float* slout = (float*)d_out + (size_t)2 * LEN * DCH;       // (2,4096,1,4,36,2)

    if (have_wt)
        hipLaunchKernelGGL(wt_kernel, dim3(64), dim3(256), 0, stream, W_out, WT);

    hipLaunchKernelGGL(corr_topk_kernel, dim3(256), dim3(512), 0, stream,
                       query, value, idxb);

    hipLaunchKernelGGL(sloc_kernel, dim3(4608), dim3(256), 0, stream, idxb, slout);

    hipLaunchKernelGGL(gather_proj_kernel, dim3(2 * LEN), dim3(128), 0, stream,
                       value, idxb,
                       have_wt ? WT : W_out, have_wt ? 1 : 0,
                       b_out, outp);
}